// Round 11
// baseline (520.337 us; speedup 1.0000x reference)
//
#include <hip/hip_runtime.h>
#include <math.h>

#define RANK 64
#define D_DIM 320          // ENT_COMPS * RANK
#define K_DIM 640          // 2 * D_DIM
#define N_ENT 80000
#define B_Q 2000
#define M_PAD 2048         // B_Q padded (zero rows 2000..2047)
#define NT32 20            // K_DIM / 32
#define SCALE_F 0.125f     // 1/sqrt(64)
#define EPS_F 1e-9f

// d_out layout (floats)
#define OFF_SCORES 0ull
#define OFF_REG0 160000000ull
#define OFF_REG1 160640000ull
#define OFF_REG2 161280000ull
#define OFF_REG3 161920000ull
#define OFF_REG4 162048000ull

typedef __attribute__((ext_vector_type(8))) short short8v;   // 8 bf16 (4 VGPRs)
typedef __attribute__((ext_vector_type(4))) float floatx4;

typedef __attribute__((address_space(1))) const unsigned int gu32;
typedef __attribute__((address_space(3))) unsigned int lu32;

#define VMCNT0() asm volatile("s_waitcnt vmcnt(0)" ::: "memory")
#define LGKM0()  asm volatile("s_waitcnt lgkmcnt(0)" ::: "memory")

static __device__ __forceinline__ unsigned short f2bf(float f) {
    union { float f; unsigned int u; } a; a.f = f;
    unsigned int u = a.u;
    u += 0x7FFFu + ((u >> 16) & 1u);   // RNE (finite inputs only)
    return (unsigned short)(u >> 16);
}

// ---------------------------------------------------------------------------
// Prep body: query row b, lane 0..63. Writes X row (bf16) + reg outputs.
// ---------------------------------------------------------------------------
static __device__ __forceinline__ void prep_row(
    int b, int lane,
    const int* __restrict__ q,
    const float* __restrict__ ent,
    const float* __restrict__ rrot_t,
    const float* __restrict__ rboost_t,
    const float* __restrict__ atten_t,
    const float* __restrict__ aux_t,
    unsigned short* __restrict__ X,
    float* __restrict__ out)
{
    unsigned short* Xrow = X + (size_t)b * K_DIM;

    if (b >= B_Q) {  // zero pad rows so MFMA tiles read clean zeros
        #pragma unroll
        for (int c = 0; c < 10; c++) Xrow[lane * 10 + c] = 0;
        return;
    }

    int h = q[3 * b + 0];
    int r = q[3 * b + 1];
    int t = q[3 * b + 2];

    const float* eh = ent + (size_t)h * K_DIM;
    const float* et = ent + (size_t)t * K_DIM;

    float4 rv = *(const float4*)(rrot_t + (size_t)r * 256 + lane * 4);
    float4 bv = *(const float4*)(rboost_t + (size_t)r * 256 + lane * 4);

    const float* xr = eh + lane * 5;
    float x0 = xr[0], x1 = xr[1], x2 = xr[2], x3 = xr[3], x4 = xr[4];

    float rr2 = rv.x * rv.x + rv.y * rv.y + rv.z * rv.z + rv.w * rv.w;
    float rb2 = bv.x * bv.x + bv.y * bv.y + bv.z * bv.z + bv.w * bv.w;

    // rotate
    float qinv = 1.0f / sqrtf(rr2 + EPS_F);
    float qw = rv.x * qinv, qx = rv.y * qinv, qy = rv.z * qinv, qz = rv.w * qinv;
    float pw = x1, px = x2, py = x3, pz = x4;
    float rot[5];
    rot[0] = x0;
    rot[1] = qw * pw - qx * px - qy * py - qz * pz;
    rot[2] = qw * px + qx * pw + qy * pz - qz * py;
    rot[3] = qw * py - qx * pz + qy * pw + qz * px;
    rot[4] = qw * pz + qx * py - qy * px + qz * pw;

    // boost
    float vn2 = fminf(fmaxf(rb2, 0.0f), 0.999f);
    float sq = sqrtf(1.0f - vn2);
    float gamma = 1.0f / sq;
    float gm1 = vn2 / (sq * (1.0f + sq));  // gamma-1 without cancellation
    float vs = bv.x * x1 + bv.y * x2 + bv.z * x3 + bv.w * x4;
    float boo[5];
    boo[0] = gamma * (x0 + vs);
    float coef = gamma * x0 + gm1 * vs / (vn2 + EPS_F);
    boo[1] = x1 + coef * bv.x;
    boo[2] = x2 + coef * bv.y;
    boo[3] = x3 + coef * bv.z;
    boo[4] = x4 + coef * bv.w;

    // attention
    const float* at = atten_t + (size_t)r * D_DIM + lane * 5;
    float w0 = at[0] * rot[0] + at[1] * rot[1] + at[2] * rot[2] + at[3] * rot[3] + at[4] * rot[4];
    float w1 = at[0] * boo[0] + at[1] * boo[1] + at[2] * boo[2] + at[3] * boo[3] + at[4] * boo[4];
    #pragma unroll
    for (int off = 32; off; off >>= 1) {
        w0 += __shfl_xor(w0, off);
        w1 += __shfl_xor(w1, off);
    }
    w0 *= SCALE_F;
    w1 *= SCALE_F;
    float mx = fmaxf(w0, w1);
    float e0 = expf(w0 - mx), e1 = expf(w1 - mx);
    float inv = 1.0f / (e0 + e1);
    float wt0 = e0 * inv, wt1 = e1 * inv;

    const float* a0p = aux_t + (size_t)r * 640 + lane * 5;
    const float* a1p = a0p + D_DIM;
    float xre[5] = {x0, x1, x2, x3, x4};

    #pragma unroll
    for (int c = 0; c < 5; c++) {
        int d = lane * 5 + c;
        float lhs = wt0 * rot[c] + wt1 * boo[c];
        float im = eh[D_DIM + d];
        float a0 = a0p[c], a1 = a1p[c];
        Xrow[d]         = f2bf(lhs * a0 - im * a1);
        Xrow[D_DIM + d] = f2bf(lhs * a1 + im * a0);
        out[OFF_REG0 + (size_t)b * D_DIM + d] = sqrtf(xre[c] * xre[c] + im * im);
        out[OFF_REG1 + (size_t)b * D_DIM + d] = sqrtf(a0 * a0 + a1 * a1);
        float tre = et[d], tim = et[D_DIM + d];
        out[OFF_REG2 + (size_t)b * D_DIM + d] = sqrtf(tre * tre + tim * tim) * (1.0f / 3.0f);
    }
    out[OFF_REG3 + (size_t)b * RANK + lane] = sqrtf(rr2);
    out[OFF_REG4 + (size_t)b * RANK + lane] = sqrtf(rb2);
}

// ---------------------------------------------------------------------------
// Fused prep + E conversion (R7/R8/R10-verified).
// ---------------------------------------------------------------------------
#define PREP_BLKS 512
#define CONV_BLKS 2048
__global__ __launch_bounds__(256) void prepconv_kernel(
    const int* __restrict__ q,
    const float* __restrict__ ent,
    const float* __restrict__ rrot_t,
    const float* __restrict__ rboost_t,
    const float* __restrict__ atten_t,
    const float* __restrict__ aux_t,
    unsigned short* __restrict__ X,
    unsigned short* __restrict__ Eb,
    float* __restrict__ out)
{
    if (blockIdx.x < PREP_BLKS) {
        int b = blockIdx.x * 4 + (threadIdx.x >> 6);   // 0..2047
        prep_row(b, threadIdx.x & 63, q, ent, rrot_t, rboost_t, atten_t, aux_t, X, out);
    } else {
        const size_t n4 = (size_t)N_ENT * K_DIM / 4;
        size_t stride = (size_t)CONV_BLKS * 256;
        for (size_t v = (size_t)(blockIdx.x - PREP_BLKS) * 256 + threadIdx.x; v < n4; v += stride) {
            float4 f = ((const float4*)ent)[v];
            ushort4 u;
            u.x = f2bf(f.x); u.y = f2bf(f.y); u.z = f2bf(f.z); u.w = f2bf(f.w);
            ((ushort4*)Eb)[v] = u;
        }
    }
}

// Standalone prep (fallback path only).
__global__ __launch_bounds__(64) void prep_kernel(
    const int* __restrict__ q, const float* __restrict__ ent,
    const float* __restrict__ rrot_t, const float* __restrict__ rboost_t,
    const float* __restrict__ atten_t, const float* __restrict__ aux_t,
    unsigned short* __restrict__ X, float* __restrict__ out)
{
    prep_row(blockIdx.x, threadIdx.x, q, ent, rrot_t, rboost_t, atten_t, aux_t, X, out);
}

// ---------------------------------------------------------------------------
// Occupancy-2 MFMA GEMM (R10 post-mortem: vmcnt depth was a no-op -> the
// stall is the per-block serialized prologue+epilogue at 1 block/CU (~10 us
// of C-store drain per block x 9.78 rounds). R8's occupancy attempt failed
// only because launch_bounds(512,4) capped VGPR at 128 < need (spill).
// Fix: size the register budget so 2 blocks/CU happens NATURALLY.)
// 256 thr / 4 waves; tile 256(M) x 128(N), per-wave 64x128: acc[4][8] =
// 128 VGPR, total ~210 -> 2 waves/SIMD with no launch_bounds cap.
// LDS: dbuf 2 x (A 256x32 = 16 KB + B 128x32 = 8 KB) = 48 KB -> 96 KB/CU.
// => 2 blocks/CU by both LDS and VGPR; co-resident block's MFMAs cover this
// block's vmcnt(0)/store drains (m114 co-scheduling).
// R3-proven single-barrier K-loop: {12 ds_read; stage other buf (6 loads);
// lgkm0; sched_barrier; 32 MFMA setprio; vmcnt0; barrier}.
// Swizzle slot^=(row>>1)&3 (R8/R9/R10 field-verified pair); all row bases
// here are multiples of 4 rows, so keys reduce identically (verified).
// Grid 5000 = 8 m-panels (bid&7 == XCD) x 625 n-blocks; exact, no clamps.
// Nontemporal C stores (keep L2 for E).
// ---------------------------------------------------------------------------
#define BUFSZ3 12288   // shorts per buffer (24 KB): A [0,8192), B [8192,12288)

__global__ __launch_bounds__(256) void gemm256x128(
    const unsigned short* __restrict__ X,   // (2048, 640) bf16
    const unsigned short* __restrict__ Eb,  // (80000, 640) bf16
    float* __restrict__ C)
{
    __shared__ unsigned short lds[2 * BUFSZ3];   // 48 KB

    const int tid = threadIdx.x;
    const int lane = tid & 63;
    const int wid = tid >> 6;         // 0..3: wave owns A-rows wid*64..+63

    const int bid = blockIdx.x;
    const int m0 = (bid & 7) * 256;        // m-panel == XCD id
    const int n0 = (bid >> 3) * 128;

    const int fr = lane & 15;
    const int kq = lane >> 4;                     // 0..3
    const int cbs8 = (kq ^ ((fr >> 1) & 3)) * 8;  // swizzled 16B slot (shorts)

    floatx4 acc[4][8];
    #pragma unroll
    for (int i = 0; i < 4; i++)
        #pragma unroll
        for (int j = 0; j < 8; j++) acc[i][j] = (floatx4)0.0f;

    int aoff[4], boff[8];
    #pragma unroll
    for (int i = 0; i < 4; i++) aoff[i] = (wid * 64 + i * 16 + fr) * 32 + cbs8;
    #pragma unroll
    for (int j = 0; j < 8; j++) boff[j] = 8192 + (j * 16 + fr) * 32 + cbs8;

    // staging: thread -> (srow = tid>>2 in 0..63, slot = tid&3); LDS dest
    // linear (tid*8 shorts per 64-row region); global k-slot pre-swizzled.
    const int srow = tid >> 2;
    const int scolg = ((tid & 3) ^ ((srow >> 1) & 3)) * 8;   // shorts

    auto stage = [&](int bufBase /*short offset*/, int kt) {
        #pragma unroll
        for (int l = 0; l < 4; l++) {   // A: 4 x 64 rows
            const unsigned short* ga = X + (size_t)(m0 + l * 64 + srow) * K_DIM + kt * 32 + scolg;
            __builtin_amdgcn_global_load_lds((gu32*)ga,
                (lu32*)&lds[bufBase + l * 2048 + tid * 8], 16, 0, 0);
        }
        #pragma unroll
        for (int l = 0; l < 2; l++) {   // B: 2 x 64 rows
            const unsigned short* gb = Eb + (size_t)(n0 + l * 64 + srow) * K_DIM + kt * 32 + scolg;
            __builtin_amdgcn_global_load_lds((gu32*)gb,
                (lu32*)&lds[bufBase + 8192 + l * 2048 + tid * 8], 16, 0, 0);
        }
    };

    // Prologue: tile 0, full drain (R4 rule: region-granular counting only).
    stage(0, 0);
    VMCNT0();
    __builtin_amdgcn_s_barrier();

    int bufo = 0;
    for (int t = 0; t < NT32; t++) {
        short8v a_[4], b_[8];
        #pragma unroll
        for (int i = 0; i < 4; i++) a_[i] = *(const short8v*)&lds[bufo + aoff[i]];
        #pragma unroll
        for (int j = 0; j < 8; j++) b_[j] = *(const short8v*)&lds[bufo + boff[j]];

        if (t < NT32 - 1) stage(bufo ^ BUFSZ3, t + 1);  // other buffer: its
        // readers' ds_reads completed before the previous barrier (WAR-safe)

        LGKM0();
        __builtin_amdgcn_sched_barrier(0);     // rule 18
        __builtin_amdgcn_s_setprio(1);
        #pragma unroll
        for (int i = 0; i < 4; i++)
            #pragma unroll
            for (int j = 0; j < 8; j++)
                acc[i][j] = __builtin_amdgcn_mfma_f32_16x16x32_bf16(
                    a_[i], b_[j], acc[i][j], 0, 0, 0);
        __builtin_amdgcn_s_setprio(0);

        VMCNT0();
        __builtin_amdgcn_s_barrier();
        bufo ^= BUFSZ3;
    }

    // Epilogue: C/D layout col=lane&15, row=(lane>>4)*4+reg (m89-verified).
    const int rb = kq * 4;
    #pragma unroll
    for (int i = 0; i < 4; i++) {
        int row = m0 + wid * 64 + i * 16 + rb;
        #pragma unroll
        for (int j = 0; j < 8; j++) {
            int col = n0 + j * 16 + fr;
            #pragma unroll
            for (int r = 0; r < 4; r++) {
                if (row + r < B_Q)
                    __builtin_nontemporal_store(acc[i][j][r],
                        &C[(size_t)(row + r) * N_ENT + col]);
            }
        }
    }
}

// ---------------------------------------------------------------------------
// Fallback GEMM (R2-verified) for ws-too-small case.
// ---------------------------------------------------------------------------
__global__ __launch_bounds__(256) void gemm_mfma_fb(
    const unsigned short* __restrict__ X,
    const float* __restrict__ Ef,
    float* __restrict__ C)
{
    __shared__ unsigned short As[128 * 32];
    __shared__ unsigned short Bs[128 * 32];

    const int tid = threadIdx.x;
    const int lane = tid & 63;
    const int wave = tid >> 6;
    const int wm = wave >> 1, wn = wave & 1;
    const int m0 = blockIdx.x * 128;
    const int n0 = blockIdx.y * 128;

    floatx4 acc[4][4];
    #pragma unroll
    for (int i = 0; i < 4; i++)
        #pragma unroll
        for (int j = 0; j < 4; j++) acc[i][j] = (floatx4)0.0f;

    const int srow = tid >> 2;
    const int scol = (tid & 3) * 8;
    const int fr = lane & 15;
    const int kb = (lane >> 4) * 8;
    const int brow_f = tid >> 1;
    const int bcol_f = (tid & 1) * 16;

    for (int k0 = 0; k0 < K_DIM; k0 += 32) {
        __syncthreads();
        #pragma unroll
        for (int r = 0; r < 2; r++) {
            const unsigned short* gp = X + (size_t)(m0 + srow + r * 64) * K_DIM + k0 + scol;
            __builtin_amdgcn_global_load_lds((gu32*)gp, (lu32*)(As + (size_t)(r * 64 + srow) * 32 + scol), 16, 0, 0);
        }
        {
            const float* ep = Ef + (size_t)(n0 + brow_f) * K_DIM + k0 + bcol_f;
            float4 f0 = *(const float4*)(ep);
            float4 f1 = *(const float4*)(ep + 4);
            float4 f2 = *(const float4*)(ep + 8);
            float4 f3 = *(const float4*)(ep + 12);
            short8v p0, p1;
            p0[0] = (short)f2bf(f0.x); p0[1] = (short)f2bf(f0.y);
            p0[2] = (short)f2bf(f0.z); p0[3] = (short)f2bf(f0.w);
            p0[4] = (short)f2bf(f1.x); p0[5] = (short)f2bf(f1.y);
            p0[6] = (short)f2bf(f1.z); p0[7] = (short)f2bf(f1.w);
            p1[0] = (short)f2bf(f2.x); p1[1] = (short)f2bf(f2.y);
            p1[2] = (short)f2bf(f2.z); p1[3] = (short)f2bf(f2.w);
            p1[4] = (short)f2bf(f3.x); p1[5] = (short)f2bf(f3.y);
            p1[6] = (short)f2bf(f3.z); p1[7] = (short)f2bf(f3.w);
            *(short8v*)(Bs + (size_t)brow_f * 32 + bcol_f) = p0;
            *(short8v*)(Bs + (size_t)brow_f * 32 + bcol_f + 8) = p1;
        }
        __syncthreads();

        short8v a[4], b[4];
        #pragma unroll
        for (int i = 0; i < 4; i++)
            a[i] = *(const short8v*)(As + (size_t)(wm * 64 + i * 16 + fr) * 32 + kb);
        #pragma unroll
        for (int j = 0; j < 4; j++)
            b[j] = *(const short8v*)(Bs + (size_t)(wn * 64 + j * 16 + fr) * 32 + kb);

        #pragma unroll
        for (int i = 0; i < 4; i++)
            #pragma unroll
            for (int j = 0; j < 4; j++)
                acc[i][j] = __builtin_amdgcn_mfma_f32_16x16x32_bf16(a[i], b[j], acc[i][j], 0, 0, 0);
    }

    const int rbase = (lane >> 4) * 4;
    #pragma unroll
    for (int i = 0; i < 4; i++) {
        #pragma unroll
        for (int j = 0; j < 4; j++) {
            int row = m0 + wm * 64 + i * 16 + rbase;
            int col = n0 + wn * 64 + j * 16 + fr;
            #pragma unroll
            for (int r = 0; r < 4; r++) {
                if (row + r < B_Q)
                    C[(size_t)(row + r) * N_ENT + col] = acc[i][j][r];
            }
        }
    }
}

extern "C" void kernel_launch(void* const* d_in, const int* in_sizes, int n_in,
                              void* d_out, int out_size, void* d_ws, size_t ws_size,
                              hipStream_t stream) {
    const int* queries = (const int*)d_in[0];
    const float* ent = (const float*)d_in[1];
    const float* rrot = (const float*)d_in[2];
    const float* rboost = (const float*)d_in[3];
    const float* atten = (const float*)d_in[4];
    const float* aux = (const float*)d_in[5];
    float* out = (float*)d_out;

    unsigned short* X = (unsigned short*)d_ws;            // 2048*640*2 = 2.62 MB
    const size_t offE = (size_t)M_PAD * K_DIM * 2;
    const size_t needE = (size_t)N_ENT * K_DIM * 2;       // 102.4 MB
    unsigned short* Eb = (unsigned short*)((char*)d_ws + offE);
    bool pre = (ws_size >= offE + needE);

    if (pre) {
        prepconv_kernel<<<PREP_BLKS + CONV_BLKS, 256, 0, stream>>>(
            queries, ent, rrot, rboost, atten, aux, X, Eb, out);
        gemm256x128<<<8 * 625, 256, 0, stream>>>(X, Eb, out + OFF_SCORES);
    } else {
        prep_kernel<<<M_PAD, 64, 0, stream>>>(queries, ent, rrot, rboost, atten, aux, X, out);
        dim3 grid(M_PAD / 128, N_ENT / 128);
        gemm_mfma_fb<<<grid, 256, 0, stream>>>(X, ent, out + OFF_SCORES);
    }
}